// Round 6
// baseline (673.778 us; speedup 1.0000x reference)
//
#include <hip/hip_runtime.h>
#include <hip/hip_bf16.h>
#include <cstdint>
#include <cstddef>

// Problem constants (from reference)
#define NBAGS  16
#define NNODES 5000
#define NEDGES 160000
#define DIN    128
#define DENC   256   // == D_GNN
#define DFC    128
#define NCLS   2

typedef __attribute__((ext_vector_type(8))) short short8;
typedef __attribute__((ext_vector_type(4))) float f32x4;

static __device__ __forceinline__ ushort f2b(float v) {
    __hip_bfloat16 b = __float2bfloat16(v);   // RNE
    return *reinterpret_cast<ushort*>(&b);
}

// ---------------------------------------------------------------------------
// bf16 MFMA GEMM: C[rows x 256] = act( A1@W1t^T (+ A2@W2t^T) + bias )
// REDUCE=true: column-sum relu(rows) into emb[bag][col] instead of storing C.
// BM=BN=128, BK=32, 256 threads = 4 waves (2x2), wave tile 64x64 via 4x4
// mfma_f32_16x16x32_bf16. LDS rows padded to 40 elems: b128 reads 2-way free.
// ---------------------------------------------------------------------------
template<bool DUAL, bool RELU, bool REDUCE>
__global__ __launch_bounds__(256)
void gemm_bf16_kernel(const ushort* __restrict__ A1, const ushort* __restrict__ Wt1,
                      const ushort* __restrict__ A2, const ushort* __restrict__ Wt2,
                      const float* __restrict__ bias, ushort* __restrict__ C,
                      float* __restrict__ emb, int rows, int K, int bagBase, int g)
{
    constexpr int LDSP = 40;
    __shared__ __align__(16) ushort As[128 * LDSP];
    __shared__ __align__(16) ushort Bs[128 * LDSP];

    const int tid  = threadIdx.x;
    const int wave = tid >> 6;
    const int lane = tid & 63;
    const int quad = lane >> 4;
    const int l16  = lane & 15;
    const int wm   = (wave >> 1) * 64;
    const int wn   = (wave & 1) * 64;
    const int row0 = blockIdx.x * 128;
    const int n0   = blockIdx.y * 128;

    f32x4 acc[4][4];
#pragma unroll
    for (int i = 0; i < 4; ++i)
#pragma unroll
        for (int j = 0; j < 4; ++j)
#pragma unroll
            for (int r = 0; r < 4; ++r) acc[i][j][r] = 0.f;

    const int sr = tid >> 1;
    const int sk = (tid & 1) * 16;

    const int npass = DUAL ? 2 : 1;
    for (int pass = 0; pass < npass; ++pass) {
        const ushort* __restrict__ A = (DUAL && pass) ? A2 : A1;
        const ushort* __restrict__ W = (DUAL && pass) ? Wt2 : Wt1;

        for (int k0 = 0; k0 < K; k0 += 32) {
            {
                uint4 v0 = make_uint4(0, 0, 0, 0), v1 = make_uint4(0, 0, 0, 0);
                const int gr = row0 + sr;
                if (gr < rows) {
                    const uint4* src = (const uint4*)(A + (size_t)gr * K + k0 + sk);
                    v0 = src[0]; v1 = src[1];
                }
                *(uint4*)&As[sr * LDSP + sk]     = v0;
                *(uint4*)&As[sr * LDSP + sk + 8] = v1;
            }
            {
                const uint4* src = (const uint4*)(W + (size_t)(n0 + sr) * K + k0 + sk);
                *(uint4*)&Bs[sr * LDSP + sk]     = src[0];
                *(uint4*)&Bs[sr * LDSP + sk + 8] = src[1];
            }
            __syncthreads();

            short8 af[4], bf[4];
#pragma unroll
            for (int t = 0; t < 4; ++t) {
                af[t] = *(const short8*)&As[(wm + t * 16 + l16) * LDSP + quad * 8];
                bf[t] = *(const short8*)&Bs[(wn + t * 16 + l16) * LDSP + quad * 8];
            }
#pragma unroll
            for (int tm = 0; tm < 4; ++tm)
#pragma unroll
                for (int tn = 0; tn < 4; ++tn)
                    acc[tm][tn] = __builtin_amdgcn_mfma_f32_16x16x32_bf16(
                        af[tm], bf[tn], acc[tm][tn], 0, 0, 0);
            __syncthreads();
        }
    }

    if (!REDUCE) {
        // epilogue: bias + relu, bf16 store. C/D: row = quad*4+reg, col = l16
#pragma unroll
        for (int tm = 0; tm < 4; ++tm) {
            const int rbase = row0 + wm + tm * 16 + quad * 4;
#pragma unroll
            for (int reg = 0; reg < 4; ++reg) {
                const int grow = rbase + reg;
                if (grow < rows) {
#pragma unroll
                    for (int tn = 0; tn < 4; ++tn) {
                        const int gcol = n0 + wn + tn * 16 + l16;
                        float v = acc[tm][tn][reg] + bias[gcol];
                        if (RELU) v = fmaxf(v, 0.f);
                        C[(size_t)grow * 256 + gcol] = f2b(v);
                    }
                }
            }
        }
    } else {
        // fused column-sum epilogue -> emb (block may straddle 2 bags)
        __shared__ float red[2][128];
        ((float*)red)[tid] = 0.f;
        __syncthreads();
        const int bagA = row0 / NNODES;
        const int boundary = (bagA + 1) * NNODES;
#pragma unroll
        for (int tn = 0; tn < 4; ++tn) {
            const int cl = wn + tn * 16 + l16;            // col within tile
            const float bv = bias[n0 + cl];
            float p0 = 0.f, p1 = 0.f;
#pragma unroll
            for (int tm = 0; tm < 4; ++tm) {
#pragma unroll
                for (int reg = 0; reg < 4; ++reg) {
                    const int grow = row0 + wm + tm * 16 + quad * 4 + reg;
                    float v = acc[tm][tn][reg] + bv;
                    if (RELU) v = fmaxf(v, 0.f);
                    if (grow < rows) {
                        if (grow >= boundary) p1 += v; else p0 += v;
                    }
                }
            }
            atomicAdd(&red[0][cl], p0);
            atomicAdd(&red[1][cl], p1);
        }
        __syncthreads();
        {
            const int slot = tid >> 7;
            const int col  = tid & 127;
            const int bag  = bagA + slot;
            if (bag < g)
                atomicAdd(&emb[(bagBase + bag) * DENC + n0 + col], red[slot][col]);
        }
    }
}

// ---------------------------------------------------------------------------
// Weight convert+transpose: Wt[n*K+k] = bf16(W[k*256+n])
// ---------------------------------------------------------------------------
__global__ __launch_bounds__(256)
void wt_transpose_kernel(const float* __restrict__ W, ushort* __restrict__ Wt, int K)
{
    const int idx = blockIdx.x * 256 + threadIdx.x;
    if (idx < 256 * K) {
        const int n = idx / K;
        const int k = idx - n * K;
        Wt[idx] = f2b(W[k * 256 + n]);
    }
}

__global__ __launch_bounds__(256)
void cvt_bf16_kernel(const float* __restrict__ x, ushort* __restrict__ xb, int n4)
{
    const int i = blockIdx.x * 256 + threadIdx.x;
    if (i < n4) {
        const float4 v = ((const float4*)x)[i];
        ushort4 o;
        o.x = f2b(v.x); o.y = f2b(v.y); o.z = f2b(v.z); o.w = f2b(v.w);
        ((ushort4*)xb)[i] = o;
    }
}

// ---------------------------------------------------------------------------
// CSR build: count -> scan -> fill. edges laid out [bag][2][E], int32.
// Bag->XCD swizzle keeps each bag's cnt/fillc/colidx in ONE XCD's L2.
// Edge streams loaded non-temporally so they don't evict dirty colidx lines.
// colidx is uint16 (src < 5000) -> half the scatter-write footprint.
// scan writes fillc=rowptr so fill's atomicAdd returns absolute positions
// (no per-edge rowptr read).
// ---------------------------------------------------------------------------
#define CSR_EPB 1024                         // edges per block
#define CSR_BPB ((NEDGES + CSR_EPB - 1) / CSR_EPB)   // 157 blocks per bag

static __device__ __forceinline__ void bag_chunk(int bx, int g, int bpb, int& bag, int& chunk)
{
    if (g == NBAGS) {
        const int half = 8 * bpb;
        const int hi = (bx >= half) ? 1 : 0;
        const int r = bx - hi * half;
        bag = (r & 7) + hi * 8;
        chunk = r >> 3;
    } else {
        bag = bx / bpb;
        chunk = bx - bag * bpb;
    }
}

__global__ __launch_bounds__(256)
void count_kernel(const int* __restrict__ edges, int* __restrict__ cnt, int g)
{
    int bag, chunk;
    bag_chunk(blockIdx.x, g, CSR_BPB, bag, chunk);
    const int* __restrict__ dstp = edges + (size_t)bag * 2 * NEDGES + NEDGES;
    int* __restrict__ cb = cnt + bag * NNODES;
    const int e0 = chunk * CSR_EPB + threadIdx.x;
    int d[4];
#pragma unroll
    for (int i = 0; i < 4; ++i) {
        const int e = e0 + i * 256;
        d[i] = (e < NEDGES) ? __builtin_nontemporal_load(&dstp[e]) : -1;
    }
#pragma unroll
    for (int i = 0; i < 4; ++i)
        if (d[i] >= 0) atomicAdd(&cb[d[i]], 1);
}

__global__ __launch_bounds__(1024)
void scan_kernel(const int* __restrict__ cnt, int* __restrict__ rowptr,
                 int* __restrict__ fillc)
{
    const int b = blockIdx.x;
    const int t = threadIdx.x;
    __shared__ int sh[1024];
    const int CH = 5;
    const int base = t * CH;
    int local[CH];
    int sum = 0;
#pragma unroll
    for (int i = 0; i < CH; ++i) {
        const int g = base + i;
        const int v = (g < NNODES) ? cnt[b * NNODES + g] : 0;
        local[i] = v; sum += v;
    }
    sh[t] = sum;
    __syncthreads();
    for (int off = 1; off < 1024; off <<= 1) {
        const int add = (t >= off) ? sh[t - off] : 0;
        __syncthreads();
        sh[t] += add;
        __syncthreads();
    }
    int run = sh[t] - sum;
#pragma unroll
    for (int i = 0; i < CH; ++i) {
        const int g = base + i;
        if (g < NNODES) {
            rowptr[b * (NNODES + 1) + g] = run;
            fillc[b * NNODES + g] = run;      // fill allocates from here
        }
        run += local[i];
    }
    if (t == 1023) rowptr[b * (NNODES + 1) + NNODES] = run;
}

__global__ __launch_bounds__(256)
void fill_kernel(const int* __restrict__ edges, int* __restrict__ fillc,
                 ushort* __restrict__ colidx, int g)
{
    int bag, chunk;
    bag_chunk(blockIdx.x, g, CSR_BPB, bag, chunk);
    const int* __restrict__ eb = edges + (size_t)bag * 2 * NEDGES;
    int* __restrict__ fc = fillc + bag * NNODES;
    ushort* __restrict__ co = colidx + (size_t)bag * NEDGES;
    const int e0 = chunk * CSR_EPB + threadIdx.x;
    int src[4], dst[4];
#pragma unroll
    for (int i = 0; i < 4; ++i) {
        const int e = e0 + i * 256;
        if (e < NEDGES) {
            src[i] = __builtin_nontemporal_load(&eb[e]);
            dst[i] = __builtin_nontemporal_load(&eb[NEDGES + e]);
        } else dst[i] = -1;
    }
#pragma unroll
    for (int i = 0; i < 4; ++i) {
        if (dst[i] >= 0) {
            const int pos = atomicAdd(&fc[dst[i]], 1);   // absolute position
            co[pos] = (ushort)src[i];
        }
    }
}

// ---------------------------------------------------------------------------
// Mean aggregation (pull), bf16 in/out, fp32 accumulate.
// One WAVE per node: 64 lanes x uint2 = 512 B = one feature row per vmem
// instr. uint16 neighbor indices (wave-uniform loads). Unroll x8 => 8 gathers
// in flight per wave. Bag->XCD swizzle keeps features L2-local.
// ---------------------------------------------------------------------------
__global__ __launch_bounds__(256)
void agg_mean_kernel(const ushort* __restrict__ X, const int* __restrict__ rowptr,
                     const ushort* __restrict__ colidx, ushort* __restrict__ M, int g)
{
    constexpr int GPB = NNODES / 4;   // node-groups per bag (4 waves/block)
    int bag, grp;
    bag_chunk(blockIdx.x, g, GPB, bag, grp);
    const int wave = threadIdx.x >> 6;
    const int lane = threadIdx.x & 63;
    const int node = grp * 4 + wave;

    const int* rp = rowptr + bag * (NNODES + 1);
    const int s = rp[node];
    const int e = rp[node + 1];
    const float inv = 1.0f / fmaxf((float)(e - s), 1.0f);
    const uint2* __restrict__ Xb = (const uint2*)(X + (size_t)bag * NNODES * DENC);
    const ushort* __restrict__ ci = colidx + (size_t)bag * NEDGES;

    float2 p0 = {0.f, 0.f}, p1 = {0.f, 0.f};
    int j = s;
    for (; j + 8 <= e; j += 8) {
        int idx[8];
#pragma unroll
        for (int t = 0; t < 8; ++t) idx[t] = ci[j + t];
        uint2 u[8];
#pragma unroll
        for (int t = 0; t < 8; ++t) u[t] = Xb[idx[t] * 64 + lane];
#pragma unroll
        for (int t = 0; t < 8; ++t) {
            p0.x += __uint_as_float(u[t].x << 16);
            p0.y += __uint_as_float(u[t].x & 0xffff0000u);
            p1.x += __uint_as_float(u[t].y << 16);
            p1.y += __uint_as_float(u[t].y & 0xffff0000u);
        }
    }
    for (; j < e; ++j) {
        const uint2 u = Xb[ci[j] * 64 + lane];
        p0.x += __uint_as_float(u.x << 16);
        p0.y += __uint_as_float(u.x & 0xffff0000u);
        p1.x += __uint_as_float(u.y << 16);
        p1.y += __uint_as_float(u.y & 0xffff0000u);
    }
    uint2 o;
    o.x = (uint32_t)f2b(p0.x * inv) | ((uint32_t)f2b(p0.y * inv) << 16);
    o.y = (uint32_t)f2b(p1.x * inv) | ((uint32_t)f2b(p1.y * inv) << 16);
    ((uint2*)(M + ((size_t)bag * NNODES + node) * DENC))[lane] = o;
}

// ---------------------------------------------------------------------------
// classifier (fp32): out[b] = relu(emb[b]@Wc1 + bc1) @ Wc2 + bc2
// ---------------------------------------------------------------------------
__global__ __launch_bounds__(128)
void classifier_kernel(const float* __restrict__ emb, const float* __restrict__ Wc1,
                       const float* __restrict__ bc1, const float* __restrict__ Wc2,
                       const float* __restrict__ bc2, float* __restrict__ out)
{
    const int b = blockIdx.x;
    const int t = threadIdx.x;  // 128
    __shared__ float se[DENC];
    se[t] = emb[b * DENC + t];
    se[128 + t] = emb[b * DENC + 128 + t];
    __syncthreads();
    float h = bc1[t];
    for (int k = 0; k < DENC; ++k) h = fmaf(se[k], Wc1[k * DFC + t], h);
    h = fmaxf(h, 0.f);
    __shared__ float s0[128], s1[128];
    s0[t] = h * Wc2[t * NCLS + 0];
    s1[t] = h * Wc2[t * NCLS + 1];
    __syncthreads();
    for (int off = 64; off > 0; off >>= 1) {
        if (t < off) { s0[t] += s0[t + off]; s1[t] += s1[t + off]; }
        __syncthreads();
    }
    if (t == 0) {
        out[b * NCLS + 0] = s0[0] + bc2[0];
        out[b * NCLS + 1] = s1[0] + bc2[1];
    }
}

// ---------------------------------------------------------------------------
extern "C" void kernel_launch(void* const* d_in, const int* in_sizes, int n_in,
                              void* d_out, int out_size, void* d_ws, size_t ws_size,
                              hipStream_t stream)
{
    const float* x    = (const float*)d_in[0];
    const int*   edges= (const int*)d_in[1];   // int32 on device
    const float* We   = (const float*)d_in[2];
    const float* be   = (const float*)d_in[3];
    const float* Wl1  = (const float*)d_in[4];
    const float* bl1  = (const float*)d_in[5];
    const float* Wr1  = (const float*)d_in[6];
    const float* Wl2  = (const float*)d_in[7];
    const float* bl2  = (const float*)d_in[8];
    const float* Wr2  = (const float*)d_in[9];
    // d_in[10..12] = Wlp, blp, Wrp: dead (softmax over 1 cluster == 1)
    const float* Wc1  = (const float*)d_in[13];
    const float* bc1  = (const float*)d_in[14];
    const float* Wc2  = (const float*)d_in[15];
    const float* bc2  = (const float*)d_in[16];
    float* out = (float*)d_out;

    auto rnd = [](size_t v) { return (v + 255) & ~(size_t)255; };
    auto bytesFor = [&](int G) -> size_t {
        size_t tot = rnd((size_t)NBAGS * NNODES * DIN * 2);             // xb
        tot += 3 * rnd((size_t)G * NNODES * DENC * 2);                  // H, Mb, Gb
        tot += rnd((size_t)256 * DIN * 2) + 4 * rnd((size_t)256 * DENC * 2); // Wt
        tot += rnd((size_t)G * (NNODES + 1) * 4);                       // rowptr
        tot += 2 * rnd((size_t)G * NNODES * 4);                         // cnt, fill
        tot += rnd((size_t)G * NEDGES * 2);                             // colidx u16
        tot += rnd((size_t)NBAGS * DENC * 4);                           // emb
        return tot + 1024;
    };
    int G = NBAGS;
    while (G > 1 && bytesFor(G) > ws_size) G >>= 1;

    char* p = (char*)d_ws;
    auto alloc = [&](size_t bytes) -> char* {
        char* r = p; p += rnd(bytes); return r;
    };
    ushort* xb    = (ushort*)alloc((size_t)NBAGS * NNODES * DIN * 2);
    ushort* H     = (ushort*)alloc((size_t)G * NNODES * DENC * 2);  // h, then mean2
    ushort* Mb    = (ushort*)alloc((size_t)G * NNODES * DENC * 2);  // mean1
    ushort* Gb    = (ushort*)alloc((size_t)G * NNODES * DENC * 2);  // g1
    ushort* Wet   = (ushort*)alloc((size_t)256 * DIN * 2);
    ushort* Wl1t  = (ushort*)alloc((size_t)256 * DENC * 2);
    ushort* Wr1t  = (ushort*)alloc((size_t)256 * DENC * 2);
    ushort* Wl2t  = (ushort*)alloc((size_t)256 * DENC * 2);
    ushort* Wr2t  = (ushort*)alloc((size_t)256 * DENC * 2);
    int*    rowptr= (int*)   alloc((size_t)G * (NNODES + 1) * 4);
    int*    cnt   = (int*)   alloc((size_t)G * NNODES * 4);
    int*    fillc = (int*)   alloc((size_t)G * NNODES * 4);
    ushort* colidx= (ushort*)alloc((size_t)G * NEDGES * 2);
    float*  emb   = (float*) alloc((size_t)NBAGS * DENC * 4);

    // one-time per launch: conversions (ws re-poisoned each call)
    hipMemsetAsync(emb, 0, (size_t)NBAGS * DENC * 4, stream);
    {
        const int n4 = NBAGS * NNODES * DIN / 4;
        cvt_bf16_kernel<<<(n4 + 255) / 256, 256, 0, stream>>>(x, xb, n4);
        wt_transpose_kernel<<<(256 * DIN + 255) / 256, 256, 0, stream>>>(We, Wet, DIN);
        wt_transpose_kernel<<<(256 * DENC + 255) / 256, 256, 0, stream>>>(Wl1, Wl1t, DENC);
        wt_transpose_kernel<<<(256 * DENC + 255) / 256, 256, 0, stream>>>(Wr1, Wr1t, DENC);
        wt_transpose_kernel<<<(256 * DENC + 255) / 256, 256, 0, stream>>>(Wl2, Wl2t, DENC);
        wt_transpose_kernel<<<(256 * DENC + 255) / 256, 256, 0, stream>>>(Wr2, Wr2t, DENC);
    }

    for (int bagBase = 0; bagBase < NBAGS; bagBase += G) {
        const int g = (bagBase + G <= NBAGS) ? G : (NBAGS - bagBase);
        const int rows = g * NNODES;
        const ushort* xg = xb + (size_t)bagBase * NNODES * DIN;
        const int*    eg = edges + (size_t)bagBase * 2 * NEDGES;

        hipMemsetAsync(cnt, 0, (size_t)g * NNODES * 4, stream);

        dim3 gemm_grid((rows + 127) / 128, 2);
        const int agg_blocks = g * (NNODES / 4);
        const int csr_blocks = g * CSR_BPB;

        // encoder: H = relu(x @ We + be)
        gemm_bf16_kernel<false, true, false><<<gemm_grid, 256, 0, stream>>>(
            xg, Wet, nullptr, nullptr, be, H, nullptr, rows, DIN, bagBase, g);

        // CSR build (shared by both SAGE layers)
        count_kernel<<<csr_blocks, 256, 0, stream>>>(eg, cnt, g);
        scan_kernel<<<g, 1024, 0, stream>>>(cnt, rowptr, fillc);
        fill_kernel<<<csr_blocks, 256, 0, stream>>>(eg, fillc, colidx, g);

        // layer 1: g1 = relu(mean1@Wl1 + h@Wr1 + bl1)
        agg_mean_kernel<<<agg_blocks, 256, 0, stream>>>(H, rowptr, colidx, Mb, g);
        gemm_bf16_kernel<true, true, false><<<gemm_grid, 256, 0, stream>>>(
            Mb, Wl1t, H, Wr1t, bl1, Gb, nullptr, rows, DENC, bagBase, g);

        // layer 2 fused with emb reduction: emb[bag] += relu(mean2@Wl2 + g1@Wr2 + bl2)
        agg_mean_kernel<<<agg_blocks, 256, 0, stream>>>(Gb, rowptr, colidx, H, g);
        gemm_bf16_kernel<true, true, true><<<gemm_grid, 256, 0, stream>>>(
            H, Wl2t, Gb, Wr2t, bl2, nullptr, emb, rows, DENC, bagBase, g);
    }

    classifier_kernel<<<NBAGS, 128, 0, stream>>>(emb, Wc1, bc1, Wc2, bc2, out);
}